// Round 1
// baseline (90.181 us; speedup 1.0000x reference)
//
#include <hip/hip_runtime.h>

// Problem constants (from reference)
#define NSTK 2
#define BB   8
#define CC   32
#define HH   128
#define WW   128
#define MM   32
#define RH   64
#define RW   64

// Output: (NSTK, BB*MM, CC, RH, RW) fp32 = 2*256*32*64*64 = 67,108,864 floats
// One thread per float4 => 2^24 threads.

__global__ __launch_bounds__(256) void roi_patch_kernel(
    const float* __restrict__ fm,      // (NSTK, BB, CC, HH, WW)
    const int*   __restrict__ boxes,   // (NSTK, BB, MM, 4) int32: x1,y1,x2,y2
    float4*      __restrict__ out)     // (NSTK, BB*MM, CC, RH, RW/4)
{
    const unsigned idx = blockIdx.x * 256u + threadIdx.x;   // 0 .. 2^24-1

    // Decompose: c4 (16) | r (64) | ch (32) | bm (256) | n (2)
    const int c4 = idx & 15;
    const int r  = (idx >> 4) & 63;
    const int ch = (idx >> 10) & 31;
    const int bm = (idx >> 15) & 255;
    const int n  = idx >> 23;

    // Box is wave-uniform for long runs of threads -> broadcast load
    const int4 bx = reinterpret_cast<const int4*>(boxes)[n * (BB * MM) + bm];
    const int x1 = bx.x, y1 = bx.y, x2 = bx.z, y2 = bx.w;

    float4 v = make_float4(0.f, 0.f, 0.f, 0.f);

    if (r < (y2 - y1)) {
        const int b = bm >> 5;                 // bm / MM
        const float* rowp = fm +
            ((((size_t)n * BB + b) * CC + ch) * HH + (size_t)(y1 + r)) * WW;
        const int cw = x2 - x1;                // valid width (8..64)
        const int c0 = c4 * 4;
        if (c0 + 3 < cw) {
            const float* p = rowp + x1 + c0;   // unaligned: 4 scalar loads (coalesced)
            v.x = p[0]; v.y = p[1]; v.z = p[2]; v.w = p[3];
        } else if (c0 < cw) {
            const float* p = rowp + x1 + c0;
            v.x = p[0];
            if (c0 + 1 < cw) v.y = p[1];
            if (c0 + 2 < cw) v.z = p[2];
            // c0+3 < cw handled by the branch above
        }
    }

    out[idx] = v;
}

extern "C" void kernel_launch(void* const* d_in, const int* in_sizes, int n_in,
                              void* d_out, int out_size, void* d_ws, size_t ws_size,
                              hipStream_t stream) {
    const float* fm    = (const float*)d_in[0];
    const int*   boxes = (const int*)d_in[1];
    float4*      out   = (float4*)d_out;

    // out_size = 67,108,864 floats -> 16,777,216 float4 -> 65536 blocks x 256
    const unsigned total_f4 = (unsigned)(out_size / 4);
    const unsigned blocks = (total_f4 + 255u) / 256u;

    roi_patch_kernel<<<blocks, 256, 0, stream>>>(fm, boxes, out);
}

// Round 3
// 53.069 us; speedup vs baseline: 1.6993x; 1.6993x over previous
//
#include <hip/hip_runtime.h>

// Problem constants (from reference)
#define NSTK 2
#define BB   8
#define CC   32
#define HH   128
#define WW   128
#define MM   32
#define RH   64
#define RW   64

typedef float f32x4 __attribute__((ext_vector_type(4)));  // native vec: OK for nontemporal builtins

// Output: (NSTK, BB*MM, CC, RH, RW) fp32 = 67,108,864 floats.
// One block per (n, bm, ch) slab: 2*256*32 = 16384 blocks x 256 threads.
// Each block writes 1024 float4 (16 KB contiguous); each thread owns
// column-quad c4 = tid&15 and rows r0, r0+16, r0+32, r0+48 (r0 = tid>>4),
// so each of its 4 stores is a fully-coalesced 1 KB/instruction wave store.
//
// Box geometry is block-uniform -> SGPR (s_load_dwordx4), and the
// "row-group entirely invalid" test (j*16 >= rh) is a scalar branch: the
// all-zero row groups skip their gather loads with zero divergence.
// All gather addresses are provably in-bounds (x1 <= 64, c <= 63, y1+r <= 127),
// so valid-region masking is branchless v_cndmask, never address clamping.

__global__ __launch_bounds__(256) void roi_patch_kernel(
    const float* __restrict__ fm,      // (NSTK, BB, CC, HH, WW)
    const int*   __restrict__ boxes,   // (NSTK, BB, MM, 4): x1,y1,x2,y2
    f32x4*       __restrict__ out)     // (NSTK, BB*MM, CC, RH, RW/4)
{
    const int slab = blockIdx.x;          // ((n*256)+bm)*32 + ch
    const int ch   = slab & 31;
    const int bmn  = slab >> 5;           // n*256 + bm
    const int bm   = bmn & 255;
    const int n    = bmn >> 8;
    const int b    = bm >> 5;             // bm / MM

    // Block-uniform box -> scalar load + SGPR broadcast
    const int4 bx = reinterpret_cast<const int4*>(boxes)[bmn];
    const int x1 = bx.x, y1 = bx.y;
    const int cw = bx.z - bx.x;           // valid width  (8..64)
    const int rh = bx.w - bx.y;           // valid height (8..64)

    const float* img = fm + (size_t)(((n * BB + b) * CC + ch) * HH) * WW;

    const int tid = threadIdx.x;
    const int c0  = (tid & 15) << 2;      // column of this thread's quad
    const int r0  = tid >> 4;             // 0..15

    // Column validity (fixed per thread across its 4 rows)
    const bool cv0 = (c0 + 0) < cw;
    const bool cv1 = (c0 + 1) < cw;
    const bool cv2 = (c0 + 2) < cw;
    const bool cv3 = (c0 + 3) < cw;

    f32x4* outp = out + ((size_t)slab << 10) + tid;
    const f32x4 zero = (f32x4){0.f, 0.f, 0.f, 0.f};

    #pragma unroll
    for (int j = 0; j < 4; ++j) {
        const int rbase = j * 16;
        if (rbase >= rh) {                // block-uniform -> scalar branch
            __builtin_nontemporal_store(zero, outp + j * 256);
            continue;
        }
        const int r = rbase + r0;
        const float* p = img + (y1 + r) * WW + x1 + c0;   // always in-bounds
        f32x4 v;
        v.x = p[0]; v.y = p[1]; v.z = p[2]; v.w = p[3];
        const bool rv = r < rh;
        v.x = (rv && cv0) ? v.x : 0.f;
        v.y = (rv && cv1) ? v.y : 0.f;
        v.z = (rv && cv2) ? v.z : 0.f;
        v.w = (rv && cv3) ? v.w : 0.f;
        __builtin_nontemporal_store(v, outp + j * 256);
    }
}

extern "C" void kernel_launch(void* const* d_in, const int* in_sizes, int n_in,
                              void* d_out, int out_size, void* d_ws, size_t ws_size,
                              hipStream_t stream) {
    const float* fm    = (const float*)d_in[0];
    const int*   boxes = (const int*)d_in[1];
    f32x4*       out   = (f32x4*)d_out;

    const int blocks = NSTK * BB * MM * CC;   // 16384 slabs
    roi_patch_kernel<<<blocks, 256, 0, stream>>>(fm, boxes, out);
}

// Round 4
// 49.078 us; speedup vs baseline: 1.8375x; 1.0813x over previous
//
#include <hip/hip_runtime.h>

// Problem constants (from reference)
#define NSTK 2
#define BB   8
#define CC   32
#define HH   128
#define WW   128
#define MM   32
#define RH   64
#define RW   64

typedef float f32x4 __attribute__((ext_vector_type(4)));

// Output: (NSTK, BB*MM, CC, RH, RW) fp32 = 67,108,864 floats.
// One block per (n, bm, channel-group-of-4): 2*256*8 = 4096 blocks x 256 threads.
// All channels of a (n,bm) share one box -> box scalar-load + geometry setup
// amortized over 4 channels; each block writes 64 KB contiguous output.
// Thread owns column-quad c0=(tid&15)*4 and rows r0,r0+16,r0+32,r0+48 per
// channel -> every store is a fully-coalesced wave-wide dwordx4 (NT, bypassing
// L2 so the L2 stays full of input feature map: per-XCD input footprint with
// the chg%8 block residue is ~4.2 MB, matching the 4 MB/XCD L2).
//
// Load predication: scalar branch skips entirely-dead row-groups (j*16 >= rh);
// per-lane exec mask skips quads that are row-dead or fully column-dead
// (c0 >= cw) so they issue no memory requests. Addresses of live loads are
// provably in-bounds (x1 <= 64, c0 <= 63 => col <= 127; y1 + r <= 127).

__global__ __launch_bounds__(256) void roi_patch_kernel(
    const float* __restrict__ fm,      // (NSTK, BB, CC, HH, WW)
    const int*   __restrict__ boxes,   // (NSTK, BB, MM, 4): x1,y1,x2,y2
    f32x4*       __restrict__ out)     // (NSTK, BB*MM, CC, RH, RW/4)
{
    const int blk = blockIdx.x;          // bmn*8 + chg
    const int chg = blk & 7;             // channel group (4 ch each)
    const int bmn = blk >> 3;            // n*256 + bm
    const int bm  = bmn & 255;
    const int n   = bmn >> 8;
    const int b   = bm >> 5;             // bm / MM

    // Block-uniform box -> scalar load + SGPR broadcast
    const int4 bx = reinterpret_cast<const int4*>(boxes)[bmn];
    const int x1 = bx.x, y1 = bx.y;
    const int cw = bx.z - bx.x;           // valid width  (8..64)
    const int rh = bx.w - bx.y;           // valid height (8..64)

    const int tid = threadIdx.x;
    const int c0  = (tid & 15) << 2;      // column of this thread's quad
    const int r0  = tid >> 4;             // 0..15

    const bool anycol = c0 < cw;          // quad has >=1 valid column (col c0)
    const bool cv1 = (c0 + 1) < cw;
    const bool cv2 = (c0 + 2) < cw;
    const bool cv3 = (c0 + 3) < cw;

    const int ch0 = chg << 2;
    const float* img0 = fm + (size_t)(((n * BB + b) * CC + ch0) * HH) * WW
                           + (y1 + r0) * WW + x1 + c0;
    f32x4* outp0 = out + ((size_t)((bmn << 5) + ch0) << 10) + tid;

    const f32x4 zero = (f32x4){0.f, 0.f, 0.f, 0.f};

    for (int ck = 0; ck < 4; ++ck) {
        const float* imgp = img0 + (size_t)ck * (HH * WW);
        f32x4* outp = outp0 + (ck << 10);
        #pragma unroll
        for (int j = 0; j < 4; ++j) {
            const int rbase = j * 16;
            if (rbase >= rh) {            // block-uniform -> scalar branch
                __builtin_nontemporal_store(zero, outp + j * 256);
                continue;
            }
            f32x4 v = zero;
            if (((rbase + r0) < rh) & anycol) {   // exec-masked: dead quads issue no loads
                const float* p = imgp + rbase * WW;
                v.x = p[0];
                v.y = cv1 ? p[1] : 0.f;
                v.z = cv2 ? p[2] : 0.f;
                v.w = cv3 ? p[3] : 0.f;
            }
            __builtin_nontemporal_store(v, outp + j * 256);
        }
    }
}

extern "C" void kernel_launch(void* const* d_in, const int* in_sizes, int n_in,
                              void* d_out, int out_size, void* d_ws, size_t ws_size,
                              hipStream_t stream) {
    const float* fm    = (const float*)d_in[0];
    const int*   boxes = (const int*)d_in[1];
    f32x4*       out   = (f32x4*)d_out;

    const int blocks = NSTK * BB * MM * (CC / 4);   // 4096
    roi_patch_kernel<<<blocks, 256, 0, stream>>>(fm, boxes, out);
}